// Round 7
// baseline (3030.258 us; speedup 1.0000x reference)
//
#include <hip/hip_runtime.h>
#include <math.h>

#define B_N 64
#define T_N 3072
#define FIN 128
#define TP 1024      // conv output length
#define COUT 64
#define HID 256
#define G4 1024      // 4*HID
#define OUT_N 10
#define NCHUNK 24
#define CHUNK_T (T_N / NCHUNK)   // 128

// 512 threads/block, thread j owns gate cols j and j+512 (256 w_hh dwords).
// Residency plan per thread (dwords): 64 named VGPR + 128 asm-forced AGPR +
// 64 LDS  -> entire w_hh on-CU, zero per-step L2 weight traffic.

typedef _Float16 h2_t __attribute__((ext_vector_type(2)));
typedef unsigned u32x4 __attribute__((ext_vector_type(4)));

#if defined(__has_builtin)
#if __has_builtin(__builtin_amdgcn_fdot2)
#define HAVE_FDOT2 1
#endif
#endif

__device__ __forceinline__ float fdot2(unsigned w, unsigned h, float acc) {
#ifdef HAVE_FDOT2
    return __builtin_amdgcn_fdot2(__builtin_bit_cast(h2_t, w),
                                  __builtin_bit_cast(h2_t, h), acc, false);
#else
    h2_t wv = __builtin_bit_cast(h2_t, w), hv = __builtin_bit_cast(h2_t, h);
    return acc + (float)wv.x * (float)hv.x + (float)wv.y * (float)hv.y;
#endif
}

__device__ __forceinline__ unsigned pack2(float a, float b) {
    unsigned la = (unsigned)__builtin_bit_cast(unsigned short, (_Float16)a);
    unsigned lb = (unsigned)__builtin_bit_cast(unsigned short, (_Float16)b);
    return la | (lb << 16);
}

// ---------------------------------------------------------------------------
// Pack w_hh to f16x2 u32x4-chunk layout for the 3 storage tiers.
//  col j   (j<512):  chunks 0..15 -> whhV[c][512];  chunks 16..31 -> whhA[c-16][512]
//  col j+512:        chunks 0..15 -> whhA[16+c][512]; chunks 16..31 -> whhL[c-16][512]
// Also wihT[k][1024] fp32 for the x-GEMM. grid 1024 (col), 128 thr (d).
// ---------------------------------------------------------------------------
__global__ void pack_weights(const float* __restrict__ w_ih,
                             const float* __restrict__ w_hh,
                             unsigned* __restrict__ whhV,   // [16][512] u32x4 flat
                             unsigned* __restrict__ whhA,   // [32][512] u32x4 flat
                             unsigned* __restrict__ whhL,   // [16][512] u32x4 flat
                             float* __restrict__ wihT) {    // [64][1024]
    int col = blockIdx.x, d = threadIdx.x;   // d = packed dword 0..127
    const float* wr = w_hh + col * HID;
    unsigned p = pack2(wr[2 * d], wr[2 * d + 1]);
    int c = d >> 2, r = d & 3;
    if (col < 512) {
        if (c < 16) whhV[((c) * 512 + col) * 4 + r] = p;
        else        whhA[((c - 16) * 512 + col) * 4 + r] = p;
    } else {
        int jj = col - 512;
        if (c < 16) whhA[((16 + c) * 512 + jj) * 4 + r] = p;
        else        whhL[((c - 16) * 512 + jj) * 4 + r] = p;
    }
    if (d < COUT) wihT[d * 1024 + col] = w_ih[col * COUT + d];
}

// conv weight permute: wc2[j][oc], j = kk*128+ic
__global__ void prep_conv_w(const float* __restrict__ conv_w, float* __restrict__ wc2) {
    int i = blockIdx.x * 256 + threadIdx.x;
    if (i < 24576) {
        int j = i >> 6, oc = i & 63;
        int kk = j >> 7, ic = j & 127;
        wc2[i] = conv_w[(oc * 128 + ic) * 3 + kk];
    }
}

// ---------------------------------------------------------------------------
// partial sum-of-squares over time (F.normalize along dim=1)
// ---------------------------------------------------------------------------
__global__ void norm_partial(const float* __restrict__ in, float* __restrict__ part) {
    int b = blockIdx.x, ch = blockIdx.y, f = threadIdx.x;
    const float* p = in + ((size_t)b * T_N + (size_t)ch * CHUNK_T) * FIN + f;
    float s0 = 0.f, s1 = 0.f, s2 = 0.f, s3 = 0.f;
#pragma unroll
    for (int r = 0; r < CHUNK_T; r += 4) {
        float v0 = p[(r + 0) * FIN];
        float v1 = p[(r + 1) * FIN];
        float v2 = p[(r + 2) * FIN];
        float v3 = p[(r + 3) * FIN];
        s0 += v0 * v0; s1 += v1 * v1; s2 += v2 * v2; s3 += v3 * v3;
    }
    part[(b * NCHUNK + ch) * FIN + f] = (s0 + s1) + (s2 + s3);
}

// ---------------------------------------------------------------------------
// normalize + conv1d(k=3,stride=3) + bias + relu  (stride==K -> GEMM)
// ---------------------------------------------------------------------------
__global__ __launch_bounds__(256) void conv_relu(
        const float* __restrict__ in, const float* __restrict__ part,
        const float* __restrict__ wc2, const float* __restrict__ cb,
        float* __restrict__ X) {
    __shared__ __align__(16) float xs[16 * 384];
    __shared__ __align__(16) float wsh[96 * 64];
    __shared__ float invn[FIN];

    int b = blockIdx.x, tile = blockIdx.y;
    int tid = threadIdx.x;

    if (tid < FIN) {
        float s = 0.f;
#pragma unroll
        for (int c = 0; c < NCHUNK; c++) s += part[(b * NCHUNK + c) * FIN + tid];
        invn[tid] = rsqrtf(fmaxf(s, 1e-24f));
    }
    __syncthreads();

    const float* ip = in + ((size_t)b * T_N + (size_t)tile * 48) * FIN;
    for (int i = tid; i < 6144; i += 256) xs[i] = ip[i] * invn[i & 127];

    int oc = tid & 63, tq = tid >> 6;
    float acc0 = 0.f, acc1 = 0.f, acc2 = 0.f, acc3 = 0.f;
    const float* xb = xs + tq * 4 * 384;

    for (int c = 0; c < 4; c++) {
        __syncthreads();
        for (int i = tid; i < 6144; i += 256) wsh[i] = wc2[c * 6144 + i];
        __syncthreads();
#pragma unroll 8
        for (int jj = 0; jj < 96; jj += 4) {
            int j = c * 96 + jj;
            float w0 = wsh[(jj + 0) * 64 + oc];
            float w1 = wsh[(jj + 1) * 64 + oc];
            float w2 = wsh[(jj + 2) * 64 + oc];
            float w3 = wsh[(jj + 3) * 64 + oc];
            float4 x0 = *(const float4*)(xb + j);
            float4 x1 = *(const float4*)(xb + 384 + j);
            float4 x2 = *(const float4*)(xb + 768 + j);
            float4 x3 = *(const float4*)(xb + 1152 + j);
            acc0 += w0 * x0.x + w1 * x0.y + w2 * x0.z + w3 * x0.w;
            acc1 += w0 * x1.x + w1 * x1.y + w2 * x1.z + w3 * x1.w;
            acc2 += w0 * x2.x + w1 * x2.y + w2 * x2.z + w3 * x2.w;
            acc3 += w0 * x3.x + w1 * x3.y + w2 * x3.z + w3 * x3.w;
        }
    }
    float bb = cb[oc];
    int tp0 = tile * 16 + tq * 4;
    size_t o = ((size_t)b * TP + tp0) * COUT + oc;
    X[o]       = fmaxf(acc0 + bb, 0.f);
    X[o + 64]  = fmaxf(acc1 + bb, 0.f);
    X[o + 128] = fmaxf(acc2 + bb, 0.f);
    X[o + 192] = fmaxf(acc3 + bb, 0.f);
}

// ---------------------------------------------------------------------------
// x-projection GEMM: xg[b,t,j] = X[b,t,:] @ w_ih[j,:] + b_ih[j] + b_hh[j],
// stored f16. grid (64 b, 64 t-tiles of 16), 256 threads.
// ---------------------------------------------------------------------------
__global__ __launch_bounds__(256) void x_gemm(
        const float* __restrict__ X, const float* __restrict__ wihT,
        const float* __restrict__ b_ih, const float* __restrict__ b_hh,
        _Float16* __restrict__ xg) {
    __shared__ float xs[64 * 17];   // [k][r], padded
    int b = blockIdx.x, t0 = blockIdx.y * 16, tid = threadIdx.x;

    const float* Xp = X + ((size_t)b * TP + t0) * COUT;
    for (int i = tid; i < 1024; i += 256) {
        int r = i >> 6, k = i & 63;
        xs[k * 17 + r] = Xp[i];
    }
    __syncthreads();

#pragma unroll
    for (int jt = 0; jt < 4; jt++) {
        int jj = jt * 256 + tid;
        float bias = b_ih[jj] + b_hh[jj];
        float acc[16];
#pragma unroll
        for (int r = 0; r < 16; r++) acc[r] = bias;
        for (int k = 0; k < 64; k++) {
            float w = wihT[k * 1024 + jj];
#pragma unroll
            for (int r = 0; r < 16; r++) acc[r] += w * xs[k * 17 + r];
        }
#pragma unroll
        for (int r = 0; r < 16; r++)
            xg[((size_t)b * TP + t0 + r) * 1024 + jj] = (_Float16)acc[r];
    }
}

// ---------------------------------------------------------------------------
// Persistent LSTM: 64 blocks x 512 threads, 1 block/CU (134 KB LDS).
// Thread j owns cols j (a0: i|f) and j+512 (a1: g|o).
// w_hh residency: 16 chunks named-VGPR (col A lo) + 32 chunks AGPR via
// explicit v_accvgpr asm (col A hi + col B lo) + 16 chunks LDS (col B hi).
// h f16 in LDS (broadcast reads); c/gates fp32; xg precomputed with bias.
// ---------------------------------------------------------------------------
__device__ __forceinline__ float fsig(float x) {
    return 1.f / (1.f + __expf(-x));
}
__device__ __forceinline__ float ftanh(float x) {
    float xc = fminf(fmaxf(x, -15.f), 15.f);
    float e = __expf(2.f * xc);
    return (e - 1.f) / (e + 1.f);
}

#define SM_WLB  0
#define SM_H    131072
#define SM_FO   131584
#define SM_H32  133632
#define SM_SIZE 134656

#define REP16(M) M(0) M(1) M(2) M(3) M(4) M(5) M(6) M(7) \
                 M(8) M(9) M(10) M(11) M(12) M(13) M(14) M(15)

// --- col-A low chunks: named VGPRs ---
#define DECLV(n)  u32x4 wr##n;
#define LOADV(n)  wr##n = whhV4[(n) * 512 + j];
#define PINV(n)   asm volatile("" : "+v"(wr##n));

// --- AGPR storage: ag = col-A chunks 16..31, bg = col-B chunks 0..15 ---
#define DECLAG(n) unsigned ag##n##_0, ag##n##_1, ag##n##_2, ag##n##_3, \
                           bg##n##_0, bg##n##_1, bg##n##_2, bg##n##_3;
#define INITAG(n) { u32x4 v = whhA4[(n) * 512 + j]; \
    asm volatile("v_accvgpr_write_b32 %0, %1" : "=a"(ag##n##_0) : "v"(v[0])); \
    asm volatile("v_accvgpr_write_b32 %0, %1" : "=a"(ag##n##_1) : "v"(v[1])); \
    asm volatile("v_accvgpr_write_b32 %0, %1" : "=a"(ag##n##_2) : "v"(v[2])); \
    asm volatile("v_accvgpr_write_b32 %0, %1" : "=a"(ag##n##_3) : "v"(v[3])); \
    v = whhA4[(16 + (n)) * 512 + j]; \
    asm volatile("v_accvgpr_write_b32 %0, %1" : "=a"(bg##n##_0) : "v"(v[0])); \
    asm volatile("v_accvgpr_write_b32 %0, %1" : "=a"(bg##n##_1) : "v"(v[1])); \
    asm volatile("v_accvgpr_write_b32 %0, %1" : "=a"(bg##n##_2) : "v"(v[2])); \
    asm volatile("v_accvgpr_write_b32 %0, %1" : "=a"(bg##n##_3) : "v"(v[3])); }

// h-chunk-major dot: each h chunk read ONCE, feeds both accumulators.
#define DOT_LO(n) { u32x4 H = hs4[n]; \
    a0 = fdot2(wr##n[0], H[0], a0); a0 = fdot2(wr##n[1], H[1], a0); \
    a0 = fdot2(wr##n[2], H[2], a0); a0 = fdot2(wr##n[3], H[3], a0); \
    unsigned w0, w1, w2, w3; \
    asm volatile("v_accvgpr_read_b32 %0, %1" : "=v"(w0) : "a"(bg##n##_0)); \
    asm volatile("v_accvgpr_read_b32 %0, %1" : "=v"(w1) : "a"(bg##n##_1)); \
    asm volatile("v_accvgpr_read_b32 %0, %1" : "=v"(w2) : "a"(bg##n##_2)); \
    asm volatile("v_accvgpr_read_b32 %0, %1" : "=v"(w3) : "a"(bg##n##_3)); \
    a1 = fdot2(w0, H[0], a1); a1 = fdot2(w1, H[1], a1); \
    a1 = fdot2(w2, H[2], a1); a1 = fdot2(w3, H[3], a1); }

#define DOT_HI(n) { u32x4 H = hs4[16 + (n)]; \
    unsigned w0, w1, w2, w3; \
    asm volatile("v_accvgpr_read_b32 %0, %1" : "=v"(w0) : "a"(ag##n##_0)); \
    asm volatile("v_accvgpr_read_b32 %0, %1" : "=v"(w1) : "a"(ag##n##_1)); \
    asm volatile("v_accvgpr_read_b32 %0, %1" : "=v"(w2) : "a"(ag##n##_2)); \
    asm volatile("v_accvgpr_read_b32 %0, %1" : "=v"(w3) : "a"(ag##n##_3)); \
    a0 = fdot2(w0, H[0], a0); a0 = fdot2(w1, H[1], a0); \
    a0 = fdot2(w2, H[2], a0); a0 = fdot2(w3, H[3], a0); \
    u32x4 W = wLB4[(n) * 512 + j]; \
    a1 = fdot2(W[0], H[0], a1); a1 = fdot2(W[1], H[1], a1); \
    a1 = fdot2(W[2], H[2], a1); a1 = fdot2(W[3], H[3], a1); }

__global__ __launch_bounds__(512) void lstm_kernel(
        const u32x4* __restrict__ whhV4, const u32x4* __restrict__ whhA4,
        const u32x4* __restrict__ whhL4,
        const _Float16* __restrict__ xg,
        const float* __restrict__ hx0, const float* __restrict__ cx0,
        const float* __restrict__ lin_w, const float* __restrict__ lin_b,
        float* __restrict__ out) {
    extern __shared__ char smem[];
    u32x4*    wLB4  = (u32x4*)(smem + SM_WLB);      // [16][512] uint4 (col-B hi)
    _Float16* h_s   = (_Float16*)(smem + SM_H);     // 256
    float2*   fo_s  = (float2*)(smem + SM_FO);      // 256: sig(f), sig(o)
    float*    h32_s = (float*)(smem + SM_H32);      // 256

    const int b = blockIdx.x, j = threadIdx.x;

    // tier 1: named VGPR chunks (col A lo)
    REP16(DECLV)
    REP16(LOADV)
    REP16(PINV)
    // tier 2: AGPR chunks via forced accvgpr writes
    REP16(DECLAG)
    REP16(INITAG)
    // tier 3: LDS chunks (col B hi)
    for (int i = j; i < 16 * 512; i += 512) wLB4[i] = whhL4[i];

    float c_reg = 0.f;
    if (j < HID) {
        c_reg = cx0[b * HID + j];
        h_s[j] = (_Float16)hx0[b * HID + j];
    }
    const _Float16* Xg = xg + (size_t)b * TP * G4;
    _Float16 xa0 = Xg[j], xa1 = Xg[j + 512];
    __syncthreads();

    const u32x4* hs4 = (const u32x4*)h_s;   // 32 chunks of 8 h-values

#pragma unroll 1
    for (int t = 0; t < TP; t++) {
        _Float16 xn0 = (_Float16)0.f, xn1 = (_Float16)0.f;
        if (t + 1 < TP) {
            xn0 = Xg[(t + 1) * G4 + j];
            xn1 = Xg[(t + 1) * G4 + j + 512];
        }

        float a0 = (float)xa0, a1 = (float)xa1;   // biases folded into xg
        REP16(DOT_LO)
        REP16(DOT_HI)

        // threads 256..511 own f (a0) and o (a1): publish pre-sigmoided
        if (j >= HID) fo_s[j - HID] = make_float2(fsig(a0), fsig(a1));
        __syncthreads();
        if (j < HID) {
            float2 fo = fo_s[j];                      // sig(f), sig(o)
            c_reg = fo.x * c_reg + fsig(a0) * ftanh(a1);   // a0=i, a1=g
            float hh = fo.y * ftanh(c_reg);
            h_s[j] = (_Float16)hh;
            if (t == TP - 1) h32_s[j] = hh;
        }
        __syncthreads();
        xa0 = xn0; xa1 = xn1;
    }

    // epilogue: out[b] = h @ lin_w.T + lin_b  (fp32 h)
    if (j < OUT_N) {
        float s = lin_b[j];
        const float* lw = lin_w + j * HID;
#pragma unroll 4
        for (int k = 0; k < HID; k++) s += h32_s[k] * lw[k];
        out[b * OUT_N + j] = s;
    }
}

// ---------------------------------------------------------------------------
extern "C" void kernel_launch(void* const* d_in, const int* in_sizes, int n_in,
                              void* d_out, int out_size, void* d_ws, size_t ws_size,
                              hipStream_t stream) {
    const float* input  = (const float*)d_in[0];
    // d_in[1] = r (unused)
    const float* hx0    = (const float*)d_in[2];
    const float* cx0    = (const float*)d_in[3];
    const float* conv_w = (const float*)d_in[4];
    const float* conv_b = (const float*)d_in[5];
    const float* w_ih   = (const float*)d_in[6];
    const float* b_ih   = (const float*)d_in[7];
    const float* w_hh   = (const float*)d_in[8];
    const float* b_hh   = (const float*)d_in[9];
    const float* lin_w  = (const float*)d_in[10];
    const float* lin_b  = (const float*)d_in[11];

    float* ws = (float*)d_ws;
    float*     part = ws;                       // 196608 floats
    float*     X    = part + 196608;            // 4194304 floats
    float*     wc2  = X + 4194304;              // 24576 floats
    float*     wihT = wc2 + 24576;              // 65536 floats
    unsigned*  whhV = (unsigned*)(wihT + 65536);   // 16*512*4 = 32768 dwords
    unsigned*  whhA = whhV + 32768;                // 32*512*4 = 65536 dwords
    unsigned*  whhL = whhA + 65536;                // 16*512*4 = 32768 dwords
    _Float16*  xg   = (_Float16*)(whhL + 32768);   // 64*1024*1024 halves

    (void)hipFuncSetAttribute((const void*)lstm_kernel,
                              hipFuncAttributeMaxDynamicSharedMemorySize, SM_SIZE);

    pack_weights<<<1024, 128, 0, stream>>>(w_ih, w_hh, whhV, whhA, whhL, wihT);
    prep_conv_w<<<96, 256, 0, stream>>>(conv_w, wc2);
    norm_partial<<<dim3(B_N, NCHUNK), FIN, 0, stream>>>(input, part);
    conv_relu<<<dim3(B_N, 64), 256, 0, stream>>>(input, part, wc2, conv_b, X);
    x_gemm<<<dim3(B_N, 64), 256, 0, stream>>>(X, wihT, b_ih, b_hh, xg);
    lstm_kernel<<<B_N, 512, SM_SIZE, stream>>>(
        (const u32x4*)whhV, (const u32x4*)whhA, (const u32x4*)whhL, xg,
        hx0, cx0, lin_w, lin_b, (float*)d_out);
}

// Round 8
// 2959.040 us; speedup vs baseline: 1.0241x; 1.0241x over previous
//
#include <hip/hip_runtime.h>
#include <math.h>

#define B_N 64
#define T_N 3072
#define FIN 128
#define TP 1024      // conv output length
#define COUT 64
#define HID 256
#define G4 1024      // 4*HID
#define OUT_N 10
#define NCHUNK 24
#define CHUNK_T (T_N / NCHUNK)   // 128

// 512 threads/block, thread j owns gate cols j and j+512 (256 w_hh dwords).
// Residency per thread (dwords): 64 named VGPR + 128 AGPR + 64 LDS.

typedef _Float16 h2_t __attribute__((ext_vector_type(2)));
typedef unsigned u32x4 __attribute__((ext_vector_type(4)));

#if defined(__has_builtin)
#if __has_builtin(__builtin_amdgcn_fdot2)
#define HAVE_FDOT2 1
#endif
#endif

__device__ __forceinline__ float fdot2(unsigned w, unsigned h, float acc) {
#ifdef HAVE_FDOT2
    return __builtin_amdgcn_fdot2(__builtin_bit_cast(h2_t, w),
                                  __builtin_bit_cast(h2_t, h), acc, false);
#else
    h2_t wv = __builtin_bit_cast(h2_t, w), hv = __builtin_bit_cast(h2_t, h);
    return acc + (float)wv.x * (float)hv.x + (float)wv.y * (float)hv.y;
#endif
}

__device__ __forceinline__ unsigned pack2(float a, float b) {
    unsigned la = (unsigned)__builtin_bit_cast(unsigned short, (_Float16)a);
    unsigned lb = (unsigned)__builtin_bit_cast(unsigned short, (_Float16)b);
    return la | (lb << 16);
}

// ---------------------------------------------------------------------------
// Pack w_hh to f16x2 u32x4-chunk layout for the 3 storage tiers (as R7).
// ---------------------------------------------------------------------------
__global__ void pack_weights(const float* __restrict__ w_ih,
                             const float* __restrict__ w_hh,
                             unsigned* __restrict__ whhV,   // [16][512] u32x4 flat
                             unsigned* __restrict__ whhA,   // [32][512] u32x4 flat
                             unsigned* __restrict__ whhL,   // [16][512] u32x4 flat
                             float* __restrict__ wihT) {    // [64][1024]
    int col = blockIdx.x, d = threadIdx.x;   // d = packed dword 0..127
    const float* wr = w_hh + col * HID;
    unsigned p = pack2(wr[2 * d], wr[2 * d + 1]);
    int c = d >> 2, r = d & 3;
    if (col < 512) {
        if (c < 16) whhV[((c) * 512 + col) * 4 + r] = p;
        else        whhA[((c - 16) * 512 + col) * 4 + r] = p;
    } else {
        int jj = col - 512;
        if (c < 16) whhA[((16 + c) * 512 + jj) * 4 + r] = p;
        else        whhL[((c - 16) * 512 + jj) * 4 + r] = p;
    }
    if (d < COUT) wihT[d * 1024 + col] = w_ih[col * COUT + d];
}

// conv weight permute: wc2[j][oc], j = kk*128+ic
__global__ void prep_conv_w(const float* __restrict__ conv_w, float* __restrict__ wc2) {
    int i = blockIdx.x * 256 + threadIdx.x;
    if (i < 24576) {
        int j = i >> 6, oc = i & 63;
        int kk = j >> 7, ic = j & 127;
        wc2[i] = conv_w[(oc * 128 + ic) * 3 + kk];
    }
}

// ---------------------------------------------------------------------------
// partial sum-of-squares over time (F.normalize along dim=1)
// ---------------------------------------------------------------------------
__global__ void norm_partial(const float* __restrict__ in, float* __restrict__ part) {
    int b = blockIdx.x, ch = blockIdx.y, f = threadIdx.x;
    const float* p = in + ((size_t)b * T_N + (size_t)ch * CHUNK_T) * FIN + f;
    float s0 = 0.f, s1 = 0.f, s2 = 0.f, s3 = 0.f;
#pragma unroll
    for (int r = 0; r < CHUNK_T; r += 4) {
        float v0 = p[(r + 0) * FIN];
        float v1 = p[(r + 1) * FIN];
        float v2 = p[(r + 2) * FIN];
        float v3 = p[(r + 3) * FIN];
        s0 += v0 * v0; s1 += v1 * v1; s2 += v2 * v2; s3 += v3 * v3;
    }
    part[(b * NCHUNK + ch) * FIN + f] = (s0 + s1) + (s2 + s3);
}

// ---------------------------------------------------------------------------
// normalize + conv1d(k=3,stride=3) + bias + relu  (stride==K -> GEMM)
// ---------------------------------------------------------------------------
__global__ __launch_bounds__(256) void conv_relu(
        const float* __restrict__ in, const float* __restrict__ part,
        const float* __restrict__ wc2, const float* __restrict__ cb,
        float* __restrict__ X) {
    __shared__ __align__(16) float xs[16 * 384];
    __shared__ __align__(16) float wsh[96 * 64];
    __shared__ float invn[FIN];

    int b = blockIdx.x, tile = blockIdx.y;
    int tid = threadIdx.x;

    if (tid < FIN) {
        float s = 0.f;
#pragma unroll
        for (int c = 0; c < NCHUNK; c++) s += part[(b * NCHUNK + c) * FIN + tid];
        invn[tid] = rsqrtf(fmaxf(s, 1e-24f));
    }
    __syncthreads();

    const float* ip = in + ((size_t)b * T_N + (size_t)tile * 48) * FIN;
    for (int i = tid; i < 6144; i += 256) xs[i] = ip[i] * invn[i & 127];

    int oc = tid & 63, tq = tid >> 6;
    float acc0 = 0.f, acc1 = 0.f, acc2 = 0.f, acc3 = 0.f;
    const float* xb = xs + tq * 4 * 384;

    for (int c = 0; c < 4; c++) {
        __syncthreads();
        for (int i = tid; i < 6144; i += 256) wsh[i] = wc2[c * 6144 + i];
        __syncthreads();
#pragma unroll 8
        for (int jj = 0; jj < 96; jj += 4) {
            int j = c * 96 + jj;
            float w0 = wsh[(jj + 0) * 64 + oc];
            float w1 = wsh[(jj + 1) * 64 + oc];
            float w2 = wsh[(jj + 2) * 64 + oc];
            float w3 = wsh[(jj + 3) * 64 + oc];
            float4 x0 = *(const float4*)(xb + j);
            float4 x1 = *(const float4*)(xb + 384 + j);
            float4 x2 = *(const float4*)(xb + 768 + j);
            float4 x3 = *(const float4*)(xb + 1152 + j);
            acc0 += w0 * x0.x + w1 * x0.y + w2 * x0.z + w3 * x0.w;
            acc1 += w0 * x1.x + w1 * x1.y + w2 * x1.z + w3 * x1.w;
            acc2 += w0 * x2.x + w1 * x2.y + w2 * x2.z + w3 * x2.w;
            acc3 += w0 * x3.x + w1 * x3.y + w2 * x3.z + w3 * x3.w;
        }
    }
    float bb = cb[oc];
    int tp0 = tile * 16 + tq * 4;
    size_t o = ((size_t)b * TP + tp0) * COUT + oc;
    X[o]       = fmaxf(acc0 + bb, 0.f);
    X[o + 64]  = fmaxf(acc1 + bb, 0.f);
    X[o + 128] = fmaxf(acc2 + bb, 0.f);
    X[o + 192] = fmaxf(acc3 + bb, 0.f);
}

// ---------------------------------------------------------------------------
// x-projection GEMM: xg[b,t,j] = X[b,t,:] @ w_ih[j,:] + b_ih[j] + b_hh[j]
// ---------------------------------------------------------------------------
__global__ __launch_bounds__(256) void x_gemm(
        const float* __restrict__ X, const float* __restrict__ wihT,
        const float* __restrict__ b_ih, const float* __restrict__ b_hh,
        _Float16* __restrict__ xg) {
    __shared__ float xs[64 * 17];   // [k][r], padded
    int b = blockIdx.x, t0 = blockIdx.y * 16, tid = threadIdx.x;

    const float* Xp = X + ((size_t)b * TP + t0) * COUT;
    for (int i = tid; i < 1024; i += 256) {
        int r = i >> 6, k = i & 63;
        xs[k * 17 + r] = Xp[i];
    }
    __syncthreads();

#pragma unroll
    for (int jt = 0; jt < 4; jt++) {
        int jj = jt * 256 + tid;
        float bias = b_ih[jj] + b_hh[jj];
        float acc[16];
#pragma unroll
        for (int r = 0; r < 16; r++) acc[r] = bias;
        for (int k = 0; k < 64; k++) {
            float w = wihT[k * 1024 + jj];
#pragma unroll
            for (int r = 0; r < 16; r++) acc[r] += w * xs[k * 17 + r];
        }
#pragma unroll
        for (int r = 0; r < 16; r++)
            xg[((size_t)b * TP + t0 + r) * 1024 + jj] = (_Float16)acc[r];
    }
}

// ---------------------------------------------------------------------------
// Persistent LSTM: 64 blocks x 512 threads, 1 block/CU.
// Storage as R7 (VGPR/AGPR/LDS tiers). R8 change: 4 INDEPENDENT partial
// accumulators per gate (R7's single 256-deep fdot2 dependency chain was the
// latency bottleneck: identical ~2.1-2.5us/step across 4 different weight
// tiers, VALUBusy ~14%), plus LDS reads hoisted to macro top for overlap.
// ---------------------------------------------------------------------------
__device__ __forceinline__ float fsig(float x) {
    return 1.f / (1.f + __expf(-x));
}
__device__ __forceinline__ float ftanh(float x) {
    float xc = fminf(fmaxf(x, -15.f), 15.f);
    float e = __expf(2.f * xc);
    return (e - 1.f) / (e + 1.f);
}

#define SM_WLB  0
#define SM_H    131072
#define SM_FO   131584
#define SM_H32  133632
#define SM_SIZE 134656

#define REP16(M) M(0) M(1) M(2) M(3) M(4) M(5) M(6) M(7) \
                 M(8) M(9) M(10) M(11) M(12) M(13) M(14) M(15)

// --- col-A low chunks: named VGPRs ---
#define DECLV(n)  u32x4 wr##n;
#define LOADV(n)  wr##n = whhV4[(n) * 512 + j];
#define PINV(n)   asm volatile("" : "+v"(wr##n));

// --- AGPR storage: ag = col-A chunks 16..31, bg = col-B chunks 0..15 ---
#define DECLAG(n) unsigned ag##n##_0, ag##n##_1, ag##n##_2, ag##n##_3, \
                           bg##n##_0, bg##n##_1, bg##n##_2, bg##n##_3;
#define INITAG(n) { u32x4 v = whhA4[(n) * 512 + j]; \
    asm volatile("v_accvgpr_write_b32 %0, %1" : "=a"(ag##n##_0) : "v"(v[0])); \
    asm volatile("v_accvgpr_write_b32 %0, %1" : "=a"(ag##n##_1) : "v"(v[1])); \
    asm volatile("v_accvgpr_write_b32 %0, %1" : "=a"(ag##n##_2) : "v"(v[2])); \
    asm volatile("v_accvgpr_write_b32 %0, %1" : "=a"(ag##n##_3) : "v"(v[3])); \
    v = whhA4[(16 + (n)) * 512 + j]; \
    asm volatile("v_accvgpr_write_b32 %0, %1" : "=a"(bg##n##_0) : "v"(v[0])); \
    asm volatile("v_accvgpr_write_b32 %0, %1" : "=a"(bg##n##_1) : "v"(v[1])); \
    asm volatile("v_accvgpr_write_b32 %0, %1" : "=a"(bg##n##_2) : "v"(v[2])); \
    asm volatile("v_accvgpr_write_b32 %0, %1" : "=a"(bg##n##_3) : "v"(v[3])); }

// lo half (h chunks 0..15): col-A from VGPR -> a0 partial p; col-B from AGPR -> a1 partial p
#define DOT_VB(n, p) { u32x4 H = hs4[n]; \
    a0_##p = fdot2(wr##n[0], H[0], a0_##p); \
    a0_##p = fdot2(wr##n[1], H[1], a0_##p); \
    a0_##p = fdot2(wr##n[2], H[2], a0_##p); \
    a0_##p = fdot2(wr##n[3], H[3], a0_##p); \
    unsigned b0, b1, b2, b3; \
    asm volatile("v_accvgpr_read_b32 %0, %1" : "=v"(b0) : "a"(bg##n##_0)); \
    asm volatile("v_accvgpr_read_b32 %0, %1" : "=v"(b1) : "a"(bg##n##_1)); \
    asm volatile("v_accvgpr_read_b32 %0, %1" : "=v"(b2) : "a"(bg##n##_2)); \
    asm volatile("v_accvgpr_read_b32 %0, %1" : "=v"(b3) : "a"(bg##n##_3)); \
    a1_##p = fdot2(b0, H[0], a1_##p); \
    a1_##p = fdot2(b1, H[1], a1_##p); \
    a1_##p = fdot2(b2, H[2], a1_##p); \
    a1_##p = fdot2(b3, H[3], a1_##p); }

// hi half (h chunks 16..31): LDS read issued FIRST (latency overlaps AGPR path);
// col-A from AGPR -> a0 partial; col-B from LDS -> a1 partial
#define DOT_AL(n, p) { u32x4 W = wLB4[(n) * 512 + j]; \
    u32x4 H = hs4[16 + (n)]; \
    unsigned g0, g1, g2, g3; \
    asm volatile("v_accvgpr_read_b32 %0, %1" : "=v"(g0) : "a"(ag##n##_0)); \
    asm volatile("v_accvgpr_read_b32 %0, %1" : "=v"(g1) : "a"(ag##n##_1)); \
    asm volatile("v_accvgpr_read_b32 %0, %1" : "=v"(g2) : "a"(ag##n##_2)); \
    asm volatile("v_accvgpr_read_b32 %0, %1" : "=v"(g3) : "a"(ag##n##_3)); \
    a0_##p = fdot2(g0, H[0], a0_##p); \
    a0_##p = fdot2(g1, H[1], a0_##p); \
    a0_##p = fdot2(g2, H[2], a0_##p); \
    a0_##p = fdot2(g3, H[3], a0_##p); \
    a1_##p = fdot2(W[0], H[0], a1_##p); \
    a1_##p = fdot2(W[1], H[1], a1_##p); \
    a1_##p = fdot2(W[2], H[2], a1_##p); \
    a1_##p = fdot2(W[3], H[3], a1_##p); }

__global__ __launch_bounds__(512) void lstm_kernel(
        const u32x4* __restrict__ whhV4, const u32x4* __restrict__ whhA4,
        const u32x4* __restrict__ whhL4,
        const _Float16* __restrict__ xg,
        const float* __restrict__ hx0, const float* __restrict__ cx0,
        const float* __restrict__ lin_w, const float* __restrict__ lin_b,
        float* __restrict__ out) {
    extern __shared__ char smem[];
    u32x4*    wLB4  = (u32x4*)(smem + SM_WLB);      // [16][512] uint4 (col-B hi)
    _Float16* h_s   = (_Float16*)(smem + SM_H);     // 256
    float2*   fo_s  = (float2*)(smem + SM_FO);      // 256: sig(f), sig(o)
    float*    h32_s = (float*)(smem + SM_H32);      // 256

    const int b = blockIdx.x, j = threadIdx.x;

    // tier 1: named VGPR chunks (col A lo)
    REP16(DECLV)
    REP16(LOADV)
    REP16(PINV)
    // tier 2: AGPR chunks
    REP16(DECLAG)
    REP16(INITAG)
    // tier 3: LDS chunks (col B hi)
    for (int i = j; i < 16 * 512; i += 512) wLB4[i] = whhL4[i];

    float c_reg = 0.f;
    if (j < HID) {
        c_reg = cx0[b * HID + j];
        h_s[j] = (_Float16)hx0[b * HID + j];
    }
    const _Float16* Xg = xg + (size_t)b * TP * G4;
    _Float16 xa0 = Xg[j], xa1 = Xg[j + 512];
    __syncthreads();

    const u32x4* hs4 = (const u32x4*)h_s;   // 32 chunks of 8 h-values

#pragma unroll 1
    for (int t = 0; t < TP; t++) {
        _Float16 xn0 = (_Float16)0.f, xn1 = (_Float16)0.f;
        if (t + 1 < TP) {
            xn0 = Xg[(t + 1) * G4 + j];
            xn1 = Xg[(t + 1) * G4 + j + 512];
        }

        // 4 independent partial accumulators per gate: chain 256 -> 64
        float a0_0 = 0.f, a0_1 = 0.f, a0_2 = 0.f, a0_3 = 0.f;
        float a1_0 = 0.f, a1_1 = 0.f, a1_2 = 0.f, a1_3 = 0.f;

        DOT_VB(0, 0)  DOT_VB(1, 1)  DOT_VB(2, 2)  DOT_VB(3, 3)
        DOT_VB(4, 0)  DOT_VB(5, 1)  DOT_VB(6, 2)  DOT_VB(7, 3)
        DOT_VB(8, 0)  DOT_VB(9, 1)  DOT_VB(10, 2) DOT_VB(11, 3)
        DOT_VB(12, 0) DOT_VB(13, 1) DOT_VB(14, 2) DOT_VB(15, 3)

        DOT_AL(0, 0)  DOT_AL(1, 1)  DOT_AL(2, 2)  DOT_AL(3, 3)
        DOT_AL(4, 0)  DOT_AL(5, 1)  DOT_AL(6, 2)  DOT_AL(7, 3)
        DOT_AL(8, 0)  DOT_AL(9, 1)  DOT_AL(10, 2) DOT_AL(11, 3)
        DOT_AL(12, 0) DOT_AL(13, 1) DOT_AL(14, 2) DOT_AL(15, 3)

        float a0 = (float)xa0 + ((a0_0 + a0_1) + (a0_2 + a0_3));
        float a1 = (float)xa1 + ((a1_0 + a1_1) + (a1_2 + a1_3));

        // threads 256..511 own f (a0) and o (a1): publish pre-sigmoided
        if (j >= HID) fo_s[j - HID] = make_float2(fsig(a0), fsig(a1));
        __syncthreads();
        if (j < HID) {
            float2 fo = fo_s[j];                           // sig(f), sig(o)
            c_reg = fo.x * c_reg + fsig(a0) * ftanh(a1);   // a0=i, a1=g
            float hh = fo.y * ftanh(c_reg);
            h_s[j] = (_Float16)hh;
            if (t == TP - 1) h32_s[j] = hh;
        }
        __syncthreads();
        xa0 = xn0; xa1 = xn1;
    }

    // epilogue: out[b] = h @ lin_w.T + lin_b  (fp32 h)
    if (j < OUT_N) {
        float s = lin_b[j];
        const float* lw = lin_w + j * HID;
#pragma unroll 4
        for (int k = 0; k < HID; k++) s += h32_s[k] * lw[k];
        out[b * OUT_N + j] = s;
    }
}

// ---------------------------------------------------------------------------
extern "C" void kernel_launch(void* const* d_in, const int* in_sizes, int n_in,
                              void* d_out, int out_size, void* d_ws, size_t ws_size,
                              hipStream_t stream) {
    const float* input  = (const float*)d_in[0];
    // d_in[1] = r (unused)
    const float* hx0    = (const float*)d_in[2];
    const float* cx0    = (const float*)d_in[3];
    const float* conv_w = (const float*)d_in[4];
    const float* conv_b = (const float*)d_in[5];
    const float* w_ih   = (const float*)d_in[6];
    const float* b_ih   = (const float*)d_in[7];
    const float* w_hh   = (const float*)d_in[8];
    const float* b_hh   = (const float*)d_in[9];
    const float* lin_w  = (const float*)d_in[10];
    const float* lin_b  = (const float*)d_in[11];

    float* ws = (float*)d_ws;
    float*     part = ws;                       // 196608 floats
    float*     X    = part + 196608;            // 4194304 floats
    float*     wc2  = X + 4194304;              // 24576 floats
    float*     wihT = wc2 + 24576;              // 65536 floats
    unsigned*  whhV = (unsigned*)(wihT + 65536);   // 16*512*4 = 32768 dwords
    unsigned*  whhA = whhV + 32768;                // 32*512*4 = 65536 dwords
    unsigned*  whhL = whhA + 65536;                // 16*512*4 = 32768 dwords
    _Float16*  xg   = (_Float16*)(whhL + 32768);   // 64*1024*1024 halves

    (void)hipFuncSetAttribute((const void*)lstm_kernel,
                              hipFuncAttributeMaxDynamicSharedMemorySize, SM_SIZE);

    pack_weights<<<1024, 128, 0, stream>>>(w_ih, w_hh, whhV, whhA, whhL, wihT);
    prep_conv_w<<<96, 256, 0, stream>>>(conv_w, wc2);
    norm_partial<<<dim3(B_N, NCHUNK), FIN, 0, stream>>>(input, part);
    conv_relu<<<dim3(B_N, 64), 256, 0, stream>>>(input, part, wc2, conv_b, X);
    x_gemm<<<dim3(B_N, 64), 256, 0, stream>>>(X, wihT, b_ih, b_hh, xg);
    lstm_kernel<<<B_N, 512, SM_SIZE, stream>>>(
        (const u32x4*)whhV, (const u32x4*)whhA, (const u32x4*)whhL, xg,
        hx0, cx0, lin_w, lin_b, (float*)d_out);
}